// Round 1
// baseline (371.912 us; speedup 1.0000x reference)
//
#include <hip/hip_runtime.h>

// Problem constants (fixed by the reference)
#define B_   4
#define L_   4096
#define H_   1024
#define N_   16
#define CH_  64             // scan chunk length
#define NC_  (L_/CH_)       // 64 chunks
#define M_   (B_*L_)        // 16384 GEMM rows
#define O2_  (2*H_)         // 2048 GEMM cols (packed pairs: 2j <- W[j], 2j+1 <- W[j+1024])
#define EPS_ 1e-6f

typedef __attribute__((ext_vector_type(4))) float  f32x4;
typedef __attribute__((ext_vector_type(8))) __bf16 bf16x8;

__device__ __forceinline__ unsigned short f2bf(float x) {
  union { float f; unsigned int u; } v; v.f = x;
  unsigned int r = v.u + 0x7FFFu + ((v.u >> 16) & 1u);   // RNE
  return (unsigned short)(r >> 16);
}
__device__ __forceinline__ float bf2f(unsigned short x) {
  union { unsigned int u; float f; } v; v.u = ((unsigned int)x) << 16;
  return v.f;
}

__device__ __forceinline__ void async_copy16(const void* g, void* l) {
  __builtin_amdgcn_global_load_lds(
      (const __attribute__((address_space(1))) unsigned int*)g,
      (__attribute__((address_space(3))) unsigned int*)l, 16, 0, 0);
}

// ---------------- K0: fused prep — SSM params + W pack->bf16 + bias pack ----
// W pack: Wp[2j][h]=W[j][h], Wp[2j+1][h]=W[j+1024][h]  (GLU partners adjacent)
__global__ void k_prep(const float* __restrict__ log_dt,
                       const float* __restrict__ log_A_real,
                       const float* __restrict__ A_imag,
                       const float* __restrict__ C_real,
                       const float* __restrict__ C_imag,
                       const float* __restrict__ outw,
                       const float* __restrict__ outb,
                       float* __restrict__ wr,  float* __restrict__ wi,
                       float* __restrict__ c2r, float* __restrict__ c2i,
                       float* __restrict__ wpr, float* __restrict__ wpi,
                       unsigned short* __restrict__ Wbf,
                       float* __restrict__ bp) {
  int idx = blockIdx.x * 256 + threadIdx.x;      // O2_*H_ threads
  int p = idx >> 10, hh = idx & (H_ - 1);
  size_t src = (size_t)((p >> 1) + (p & 1) * H_) * H_ + hh;
  Wbf[idx] = f2bf(outw[src]);
  if (idx < O2_) bp[idx] = outb[(idx >> 1) + (idx & 1) * H_];
  if (idx < H_ * N_) {
    int h = idx / N_, n = idx % N_;
    int hn = h * N_ + n;
    float dt  = expf(log_dt[h]);
    float Ar  = -expf(log_A_real[hn]);
    float Ai  = A_imag[hn];
    float dr  = Ar * dt, di = Ai * dt;          // dtA
    float er  = expf(dr);
    float wrv = er * cosf(di), wiv = er * sinf(di);   // w = exp(dtA)
    float e1r = wrv - 1.0f, e1i = wiv;                // exp(dtA)-1
    float den = Ar * Ar + Ai * Ai;
    float qr  = (e1r * Ar + e1i * Ai) / den;          // (exp(dtA)-1)/A
    float qi  = (e1i * Ar - e1r * Ai) / den;
    float Cr  = C_real[hn], Ci = C_imag[hn];
    float cdr = Cr * qr - Ci * qi;
    float cdi = Cr * qi + Ci * qr;
    float ep  = expf((float)CH_ * dr);
    int o = n * H_ + h;                                // [n][h] (lane-coalesced)
    wr[o]  = wrv;  wi[o]  = wiv;
    c2r[o] = 2.0f * cdr; c2i[o] = 2.0f * cdi;
    wpr[o] = ep * cosf((float)CH_ * di);
    wpi[o] = ep * sinf((float)CH_ * di);
  }
}

// ---------------- K1: per-row RMSNorm scale = rsqrt(mean(h^2)+eps)*mask -----
__global__ __launch_bounds__(256) void k_scale(const float* __restrict__ hs,
                                               const float* __restrict__ mask,
                                               float* __restrict__ scale) {
  int m = blockIdx.x, tid = threadIdx.x;
  float4 v = reinterpret_cast<const float4*>(hs + (size_t)m * H_)[tid];
  float s = v.x * v.x + v.y * v.y + v.z * v.z + v.w * v.w;
  #pragma unroll
  for (int off = 32; off > 0; off >>= 1) s += __shfl_down(s, off, 64);
  __shared__ float ps[4];
  if ((tid & 63) == 0) ps[tid >> 6] = s;
  __syncthreads();
  if (tid == 0) {
    float var = (ps[0] + ps[1] + ps[2] + ps[3]) * (1.0f / H_);
    scale[m] = rsqrtf(var + EPS_) * mask[m];
  }
}

// ---------------- K2: pass 1 — local end states + u (bf16) ------------------
__global__ __launch_bounds__(256) void k_scan1(const float* __restrict__ hs,
                                               const float* __restrict__ nw,
                                               const float* __restrict__ scale,
                                               const float* __restrict__ wr_,
                                               const float* __restrict__ wi_,
                                               float* __restrict__ endr,
                                               float* __restrict__ endi,
                                               unsigned short* __restrict__ ubf) {
  int tid = threadIdx.x;
  int h = blockIdx.x * 256 + tid;
  int c = blockIdx.y, b = blockIdx.z;
  float wr[N_], wi[N_], xr[N_], xi[N_];
  #pragma unroll
  for (int n = 0; n < N_; n++) {
    wr[n] = wr_[n * H_ + h]; wi[n] = wi_[n * H_ + h];
    xr[n] = 0.f; xi[n] = 0.f;
  }
  float nwh = nw[h];
  int l0 = c * CH_;
  const float* scp = scale + (size_t)b * L_ + l0;   // block-uniform per l
  const float* hp = hs + ((size_t)b * L_ + l0) * H_ + h;
  unsigned short* up = ubf + ((size_t)b * L_ + l0) * H_ + h;
  #pragma unroll 8
  for (int l = 0; l < CH_; l++) {
    float u = hp[(size_t)l * H_] * scp[l] * nwh;
    unsigned short ub = f2bf(u);
    up[(size_t)l * H_] = ub;
    u = bf2f(ub);                 // keep scan consistent with stored u
    #pragma unroll
    for (int n = 0; n < N_; n++) {
      float oxr = xr[n];
      xr[n] = fmaf(wr[n], oxr, fmaf(-wi[n], xi[n], u));
      xi[n] = fmaf(wr[n], xi[n], wi[n] * oxr);
    }
  }
  size_t base = (((size_t)b * NC_ + c) * N_) * H_ + h;
  #pragma unroll
  for (int n = 0; n < N_; n++) {
    endr[base + (size_t)n * H_] = xr[n];
    endi[base + (size_t)n * H_] = xi[n];
  }
}

// ---------------- K3: pass 2 — carry scan, parallel over (b,n,h) ------------
__global__ __launch_bounds__(256) void k_carry(const float* __restrict__ wpr_,
                                               const float* __restrict__ wpi_,
                                               const float* __restrict__ endr,
                                               const float* __restrict__ endi,
                                               float* __restrict__ carr,
                                               float* __restrict__ cari) {
  int idx = blockIdx.x * 256 + threadIdx.x;   // B_*N_*H_ = 65536
  int h = idx & (H_ - 1);
  int n = (idx >> 10) & (N_ - 1);
  int b = idx >> 14;
  float wprv = wpr_[n * H_ + h], wpiv = wpi_[n * H_ + h];
  float sr = 0.f, si = 0.f;
  size_t cstride = (size_t)N_ * H_;
  size_t base = ((size_t)b * NC_) * cstride + (size_t)n * H_ + h;
  for (int c = 0; c < NC_; c++, base += cstride) {
    carr[base] = sr; cari[base] = si;
    float er = endr[base], ei = endi[base];
    float osr = sr;
    sr = fmaf(wprv, osr,  fmaf(-wpiv, si, er));
    si = fmaf(wprv, si, fmaf(wpiv, osr, ei));
  }
}

// ---------------- K4: pass 3 — n-outer re-scan from LDS u-tile --------------
__global__ __launch_bounds__(256) void k_scan2(const unsigned short* __restrict__ ubf,
                                               const float* __restrict__ wr_,
                                               const float* __restrict__ wi_,
                                               const float* __restrict__ c2r_,
                                               const float* __restrict__ c2i_,
                                               const float* __restrict__ Dp,
                                               const float* __restrict__ carr,
                                               const float* __restrict__ cari,
                                               unsigned short* __restrict__ ybf) {
  __shared__ __align__(16) unsigned short us[CH_ * 256];   // 32KB
  int tid = threadIdx.x;
  int hb = blockIdx.x;                 // h-block (4 of 256)
  int c = blockIdx.y, b = blockIdx.z;
  int h = hb * 256 + tid;
  int l0 = c * CH_;
  const unsigned short* usrc = ubf + ((size_t)b * L_ + l0) * H_ + hb * 256;
  #pragma unroll
  for (int i = 0; i < 8; i++) {
    int g = i * 256 + tid;
    int l = g >> 5, hq = (g & 31) * 8;
    async_copy16(usrc + (size_t)l * H_ + hq, &us[g * 8]);
  }
  __syncthreads();

  float yacc[CH_];
  float Dh = Dp[h];
  #pragma unroll
  for (int l = 0; l < CH_; l++)
    yacc[l] = Dh * bf2f(us[l * 256 + tid]);

  size_t base = (((size_t)b * NC_ + c) * N_) * H_ + h;
  for (int n = 0; n < N_; n++) {
    float wrv = wr_[n * H_ + h],  wiv = wi_[n * H_ + h];
    float crv = c2r_[n * H_ + h], civ = c2i_[n * H_ + h];
    float xr = carr[base + (size_t)n * H_];
    float xi = cari[base + (size_t)n * H_];
    #pragma unroll
    for (int l = 0; l < CH_; l++) {
      float u = bf2f(us[l * 256 + tid]);
      float oxr = xr;
      xr = fmaf(wrv, oxr, fmaf(-wiv, xi, u));
      xi = fmaf(wrv, xi, wiv * oxr);
      yacc[l] = fmaf(crv, xr, fmaf(-civ, xi, yacc[l]));
    }
  }
  unsigned short* yp = ybf + ((size_t)b * L_ + l0) * H_ + h;
  #pragma unroll
  for (int l = 0; l < CH_; l++) {
    float yv = yacc[l];
    float g = 0.5f * yv * (1.0f + erff(yv * 0.70710678118654752f));
    yp[(size_t)l * H_] = f2bf(g);
  }
}

// ---------------- K5: 256x256 8-phase GEMM + fused GLU/bias/residual --------
// T3+T4 port of the m201 template: BK=64, 512 thr (2x4 waves), per-wave
// 128x64 output (acc[8][4]). LDS = 2 dbuf x (A 256x64 + B 256x64) bf16 =
// 128 KiB (dynamic). Per phase: 12 ds_read_b128 (one C-quadrant, K=64) +
// one half-tile global_load_lds stage -> barrier -> lgkmcnt(0) -> setprio(1)
// + 16 MFMA + setprio(0) -> barrier. Counted vmcnt(4) only at phases 4/8.
//
// Region schedule (phases of one iteration; t0=2i buf0, t1=2i+1 buf1):
//   compute: ph0 (b0,mLO,nEV) ph1 (b0,mLO,nOD) ph2 (b0,mHI,nOD) ph3 (b0,mHI,nEV)
//            ph4 (b1,mLO,nEV) ph5 (b1,mLO,nOD) ph6 (b1,mHI,nOD) ph7 (b1,mHI,nEV)
//   stage:   ph0 A1hi(t1) ph1 B1ev(t1) ph2 A0lo(t2) ph3 B0od(t2)+VM4
//            ph4 A0hi(t2) ph5 B0ev(t2) ph6 A1lo(t3) ph7 B1od(t3)+VM4
// Every stage target's last reader finished >=1 barrier earlier; every
// consumer is covered by the preceding vmcnt(4)+barrier (4 loads = the last
// 2 stages remain in flight). MFMA K-order per output element is identical
// to the previous 2-barrier kernel -> bit-identical result.
#define BM2 256
#define BN2 256
#define NT2 16              // K tiles (K=1024, BK=64)
#define GST 132             // epilogue fp32 row stride (16B-aligned, 128 cols)
#define GEMM_LDS 131072

#define STAGE_A(buf, half, kt) do { \
  async_copy16(Ag + (size_t)(bm + rp0 + ((half) << 6)) * H_ + (kt) * 64 + ca0, \
               sA + (buf) * 32768 + ((half) << 13) + tid * 16); \
  async_copy16(Ag + (size_t)(bm + rp1 + 64 + ((half) << 6)) * H_ + (kt) * 64 + ca1, \
               sA + (buf) * 32768 + ((half) << 13) + 16384 + tid * 16); \
} while (0)

#define STAGE_B(buf, eo, kt) do { \
  async_copy16(Bg + (size_t)(bn + ((rp0 >> 5) << 6) + (rp0 & 31) + ((eo) << 5)) * H_ + (kt) * 64 + ca0, \
               sB + (buf) * 32768 + ((rp0 >> 5) << 13) + ((rp0 & 31) << 7) + ((eo) << 12) + (q0 << 4)); \
  async_copy16(Bg + (size_t)(bn + ((rp1 >> 5) << 6) + (rp1 & 31) + ((eo) << 5)) * H_ + (kt) * 64 + ca1, \
               sB + (buf) * 32768 + ((rp1 >> 5) << 13) + ((rp1 & 31) << 7) + ((eo) << 12) + (q0 << 4)); \
} while (0)

#define VM4  asm volatile("s_waitcnt vmcnt(4)" ::: "memory")
#define NOVM do {} while (0)

#define PHASE(buf, mh, nh, STAGE_STMT, CLOSE_STMT) do { \
  bf16x8 af[4][2], bfr[2][2]; \
  _Pragma("unroll") \
  for (int m2 = 0; m2 < 4; m2++) { \
    _Pragma("unroll") \
    for (int kk = 0; kk < 2; kk++) \
      af[m2][kk] = *reinterpret_cast<const bf16x8*>( \
          sA + (buf) * 32768 + (((wm << 7) + ((mh) << 6) + (m2 << 4)) << 7) + aoff[kk]); \
  } \
  _Pragma("unroll") \
  for (int n2 = 0; n2 < 2; n2++) { \
    _Pragma("unroll") \
    for (int kk = 0; kk < 2; kk++) \
      bfr[n2][kk] = *reinterpret_cast<const bf16x8*>( \
          sB + (buf) * 32768 + (((wn << 6) + ((nh) << 5) + (n2 << 4)) << 7) + aoff[kk]); \
  } \
  STAGE_STMT; \
  asm volatile("" ::: "memory"); \
  __builtin_amdgcn_s_barrier(); \
  asm volatile("s_waitcnt lgkmcnt(0)" ::: "memory"); \
  __builtin_amdgcn_sched_barrier(0); \
  __builtin_amdgcn_s_setprio(1); \
  _Pragma("unroll") \
  for (int m2 = 0; m2 < 4; m2++) { \
    _Pragma("unroll") \
    for (int n2 = 0; n2 < 2; n2++) { \
      _Pragma("unroll") \
      for (int kk = 0; kk < 2; kk++) \
        acc[(mh) * 4 + m2][(nh) * 2 + n2] = __builtin_amdgcn_mfma_f32_16x16x32_bf16( \
            af[m2][kk], bfr[n2][kk], acc[(mh) * 4 + m2][(nh) * 2 + n2], 0, 0, 0); \
    } \
  } \
  __builtin_amdgcn_s_setprio(0); \
  CLOSE_STMT; \
  asm volatile("" ::: "memory"); \
  __builtin_amdgcn_s_barrier(); \
  asm volatile("" ::: "memory"); \
} while (0)

__global__ __launch_bounds__(512, 2) void k_gemm(const unsigned short* __restrict__ Ag,
                                                 const unsigned short* __restrict__ Bg,
                                                 const float* __restrict__ bp,
                                                 const float* __restrict__ hs,
                                                 float* __restrict__ out) {
  extern __shared__ __align__(16) char smem[];
  char* sA = smem;                       // [2][256][64] bf16 = 64KB
  char* sB = smem + 65536;               // [2][256][64] bf16 = 64KB
  const int tid  = threadIdx.x;
  const int lane = tid & 63;
  const int wave = tid >> 6;
  const int wm = wave >> 2;              // 0..1  (row half, 128 rows)
  const int wn = wave & 3;               // 0..3  (col quarter, 64 cols)
  const int bn = blockIdx.x * BN2;
  const int bm = blockIdx.y * BM2;
  const int ar = lane & 15, kqi = lane >> 4;

  // staging constants: issue i covers chunks i*512+tid; r' = chunk>>3
  const int rp0 = tid >> 3, q0 = tid & 7;
  const int rp1 = rp0 + 64;
  const int ca0 = (q0 ^ (rp0 & 7)) * 8;  // pre-swizzled source col (elements)
  const int ca1 = (q0 ^ (rp1 & 7)) * 8;
  // ds_read offsets: row&7 == ar&7 for every fragment row -> per-thread const
  int aoff[2];
  #pragma unroll
  for (int kk = 0; kk < 2; kk++)
    aoff[kk] = ar * 128 + (((kk * 4 + kqi) ^ (ar & 7)) << 4);

  f32x4 acc[8][4];
  #pragma unroll
  for (int mi = 0; mi < 8; mi++)
    #pragma unroll
    for (int ni = 0; ni < 4; ni++) acc[mi][ni] = (f32x4){0.f, 0.f, 0.f, 0.f};

  // prologue: tile0 fully into buf0, then A-LOW/B-ODD of tile1 into buf1.
  // vmcnt(4) drains tile0's 4 stages, leaves tile1's 2 in flight.
  STAGE_A(0, 0, 0);
  STAGE_B(0, 0, 0);
  STAGE_A(0, 1, 0);
  STAGE_B(0, 1, 0);
  STAGE_A(1, 0, 1);
  STAGE_B(1, 1, 1);
  VM4;
  __builtin_amdgcn_s_barrier();
  asm volatile("" ::: "memory");

  #pragma unroll 1
  for (int i = 0; i < NT2 / 2; i++) {
    const int tb = 2 * i + 1;
    const int tc = (2 * i + 2 < NT2) ? 2 * i + 2 : NT2 - 1;  // clamped: last-iter
    const int td = (2 * i + 3 < NT2) ? 2 * i + 3 : NT2 - 1;  // stages are benign
    PHASE(0, 0, 0, STAGE_A(1, 1, tb), NOVM);
    PHASE(0, 0, 1, STAGE_B(1, 0, tb), NOVM);
    PHASE(0, 1, 1, STAGE_A(0, 0, tc), NOVM);
    PHASE(0, 1, 0, STAGE_B(0, 1, tc), VM4);
    PHASE(1, 0, 0, STAGE_A(0, 1, tc), NOVM);
    PHASE(1, 0, 1, STAGE_B(0, 0, tc), NOVM);
    PHASE(1, 1, 1, STAGE_A(1, 0, td), NOVM);
    PHASE(1, 1, 0, STAGE_B(1, 1, td), VM4);
  }
  asm volatile("s_waitcnt vmcnt(0)" ::: "memory");   // drain before LDS reuse
  __builtin_amdgcn_s_barrier();
  asm volatile("" ::: "memory");

  // Epilogue in two 128-row halves (gt = 128 x GST fp32 = 66KB, reuses smem).
  // C/D layout: col = lane&15, row = (lane>>4)*4 + reg. Even packed col p =
  // GLU 'a', odd = 'b' (adjacent lane, same row).
  float* gt = (float*)smem;
  #pragma unroll
  for (int hf = 0; hf < 2; hf++) {
    if (wm == hf) {
      #pragma unroll
      for (int ni = 0; ni < 4; ni++) {
        int p  = wn * 64 + ni * 16 + (lane & 15);
        int pe = (bn + p) & ~1;
        float bA = bp[pe], bB = bp[pe + 1];
        int jl = p >> 1;
        #pragma unroll
        for (int mi = 0; mi < 8; mi++) {
          int lrow0 = mi * 16 + (lane >> 4) * 4;
          #pragma unroll
          for (int r = 0; r < 4; r++) {
            float v = acc[mi][ni][r];
            float w = __shfl_xor(v, 1, 64);
            if (!(lane & 1))
              gt[(lrow0 + r) * GST + jl] = (v + bA) / (1.0f + __expf(-(w + bB)));
          }
        }
      }
    }
    __syncthreads();
    {
      const int c4 = tid & 31;             // 32 float4 = 128 output cols
      const int rw = tid >> 5;             // 0..15
      const size_t obase = (size_t)(bm + hf * 128) * H_ + (bn >> 1);
      #pragma unroll
      for (int rep = 0; rep < 8; rep++) {
        int row = rep * 16 + rw;
        float4 g = *reinterpret_cast<const float4*>(&gt[row * GST + c4 * 4]);
        size_t o = obase + (size_t)row * H_ + c4 * 4;
        float4 hv = *reinterpret_cast<const float4*>(&hs[o]);
        float4 rv = {hv.x + g.x, hv.y + g.y, hv.z + g.z, hv.w + g.w};
        *reinterpret_cast<float4*>(&out[o]) = rv;
      }
    }
    __syncthreads();
  }
}

extern "C" void kernel_launch(void* const* d_in, const int* in_sizes, int n_in,
                              void* d_out, int out_size, void* d_ws, size_t ws_size,
                              hipStream_t stream) {
  const float* hs    = (const float*)d_in[0];
  const float* mask  = (const float*)d_in[1];
  const float* nw    = (const float*)d_in[2];
  const float* ldt   = (const float*)d_in[3];
  const float* lar   = (const float*)d_in[4];
  const float* aim   = (const float*)d_in[5];
  const float* crl   = (const float*)d_in[6];
  const float* cim   = (const float*)d_in[7];
  const float* Dp    = (const float*)d_in[8];
  const float* outw  = (const float*)d_in[9];
  const float* outb  = (const float*)d_in[10];
  float* out = (float*)d_out;

  static bool attr_done = false;
  if (!attr_done) {
    hipFuncSetAttribute((const void*)k_gemm,
                        hipFuncAttributeMaxDynamicSharedMemorySize, GEMM_LDS);
    attr_done = true;
  }

  size_t off = 0;
  char* ws = (char*)d_ws;
  auto nxt = [&](size_t bytes) -> void* {
    void* p = ws + off; off += (bytes + 255) & ~(size_t)255; return p;
  };
  float* wr   = (float*)nxt(H_ * N_ * 4);
  float* wi   = (float*)nxt(H_ * N_ * 4);
  float* c2r  = (float*)nxt(H_ * N_ * 4);
  float* c2i  = (float*)nxt(H_ * N_ * 4);
  float* wpr  = (float*)nxt(H_ * N_ * 4);
  float* wpi  = (float*)nxt(H_ * N_ * 4);
  float* bpck = (float*)nxt(O2_ * 4);
  float* scale= (float*)nxt((size_t)M_ * 4);
  float* endr = (float*)nxt((size_t)B_ * NC_ * N_ * H_ * 4);
  float* endi = (float*)nxt((size_t)B_ * NC_ * N_ * H_ * 4);
  float* carr = (float*)nxt((size_t)B_ * NC_ * N_ * H_ * 4);
  float* cari = (float*)nxt((size_t)B_ * NC_ * N_ * H_ * 4);
  unsigned short* Wbf = (unsigned short*)nxt((size_t)O2_ * H_ * 2);
  unsigned short* ubf = (unsigned short*)nxt((size_t)M_ * H_ * 2);
  unsigned short* ybf = (unsigned short*)nxt((size_t)M_ * H_ * 2);

  k_prep<<<dim3(O2_ * H_ / 256), dim3(256), 0, stream>>>(ldt, lar, aim, crl, cim,
                                                         outw, outb,
                                                         wr, wi, c2r, c2i, wpr, wpi,
                                                         Wbf, bpck);
  k_scale<<<dim3(M_), dim3(256), 0, stream>>>(hs, mask, scale);
  k_scan1<<<dim3(H_ / 256, NC_, B_), dim3(256), 0, stream>>>(hs, nw, scale, wr, wi,
                                                             endr, endi, ubf);
  k_carry<<<dim3(B_ * N_ * H_ / 256), dim3(256), 0, stream>>>(wpr, wpi, endr, endi, carr, cari);
  k_scan2<<<dim3(H_ / 256, NC_, B_), dim3(256), 0, stream>>>(ubf, wr, wi, c2r, c2i,
                                                             Dp, carr, cari, ybf);
  k_gemm<<<dim3(O2_ / BN2, M_ / BM2), dim3(512), GEMM_LDS, stream>>>(ybf, Wbf, bpck, hs, out);
}

// Round 2
// 369.036 us; speedup vs baseline: 1.0078x; 1.0078x over previous
//
#include <hip/hip_runtime.h>

// Problem constants (fixed by the reference)
#define B_   4
#define L_   4096
#define H_   1024
#define N_   16
#define CH_  64             // scan chunk length
#define NC_  (L_/CH_)       // 64 chunks
#define M_   (B_*L_)        // 16384 GEMM rows
#define O2_  (2*H_)         // 2048 GEMM cols (packed pairs: 2j <- W[j], 2j+1 <- W[j+1024])
#define EPS_ 1e-6f

typedef __attribute__((ext_vector_type(4))) float  f32x4;
typedef __attribute__((ext_vector_type(8))) __bf16 bf16x8;

__device__ __forceinline__ unsigned short f2bf(float x) {
  union { float f; unsigned int u; } v; v.f = x;
  unsigned int r = v.u + 0x7FFFu + ((v.u >> 16) & 1u);   // RNE
  return (unsigned short)(r >> 16);
}
__device__ __forceinline__ float bf2f(unsigned short x) {
  union { unsigned int u; float f; } v; v.u = ((unsigned int)x) << 16;
  return v.f;
}

__device__ __forceinline__ void async_copy16(const void* g, void* l) {
  __builtin_amdgcn_global_load_lds(
      (const __attribute__((address_space(1))) unsigned int*)g,
      (__attribute__((address_space(3))) unsigned int*)l, 16, 0, 0);
}

// ---------------- K0: fused prep — SSM params + W pack->bf16 + bias pack ----
// W pack: Wp[2j][h]=W[j][h], Wp[2j+1][h]=W[j+1024][h]  (GLU partners adjacent)
__global__ void k_prep(const float* __restrict__ log_dt,
                       const float* __restrict__ log_A_real,
                       const float* __restrict__ A_imag,
                       const float* __restrict__ C_real,
                       const float* __restrict__ C_imag,
                       const float* __restrict__ outw,
                       const float* __restrict__ outb,
                       float* __restrict__ wr,  float* __restrict__ wi,
                       float* __restrict__ c2r, float* __restrict__ c2i,
                       float* __restrict__ wpr, float* __restrict__ wpi,
                       unsigned short* __restrict__ Wbf,
                       float* __restrict__ bp) {
  int idx = blockIdx.x * 256 + threadIdx.x;      // O2_*H_ threads
  int p = idx >> 10, hh = idx & (H_ - 1);
  size_t src = (size_t)((p >> 1) + (p & 1) * H_) * H_ + hh;
  Wbf[idx] = f2bf(outw[src]);
  if (idx < O2_) bp[idx] = outb[(idx >> 1) + (idx & 1) * H_];
  if (idx < H_ * N_) {
    int h = idx / N_, n = idx % N_;
    int hn = h * N_ + n;
    float dt  = expf(log_dt[h]);
    float Ar  = -expf(log_A_real[hn]);
    float Ai  = A_imag[hn];
    float dr  = Ar * dt, di = Ai * dt;          // dtA
    float er  = expf(dr);
    float wrv = er * cosf(di), wiv = er * sinf(di);   // w = exp(dtA)
    float e1r = wrv - 1.0f, e1i = wiv;                // exp(dtA)-1
    float den = Ar * Ar + Ai * Ai;
    float qr  = (e1r * Ar + e1i * Ai) / den;          // (exp(dtA)-1)/A
    float qi  = (e1i * Ar - e1r * Ai) / den;
    float Cr  = C_real[hn], Ci = C_imag[hn];
    float cdr = Cr * qr - Ci * qi;
    float cdi = Cr * qi + Ci * qr;
    float ep  = expf((float)CH_ * dr);
    int o = n * H_ + h;                                // [n][h] (lane-coalesced)
    wr[o]  = wrv;  wi[o]  = wiv;
    c2r[o] = 2.0f * cdr; c2i[o] = 2.0f * cdi;
    wpr[o] = ep * cosf((float)CH_ * di);
    wpi[o] = ep * sinf((float)CH_ * di);
  }
}

// ---------------- K1: per-row RMSNorm scale = rsqrt(mean(h^2)+eps)*mask -----
__global__ __launch_bounds__(256) void k_scale(const float* __restrict__ hs,
                                               const float* __restrict__ mask,
                                               float* __restrict__ scale) {
  int m = blockIdx.x, tid = threadIdx.x;
  float4 v = reinterpret_cast<const float4*>(hs + (size_t)m * H_)[tid];
  float s = v.x * v.x + v.y * v.y + v.z * v.z + v.w * v.w;
  #pragma unroll
  for (int off = 32; off > 0; off >>= 1) s += __shfl_down(s, off, 64);
  __shared__ float ps[4];
  if ((tid & 63) == 0) ps[tid >> 6] = s;
  __syncthreads();
  if (tid == 0) {
    float var = (ps[0] + ps[1] + ps[2] + ps[3]) * (1.0f / H_);
    scale[m] = rsqrtf(var + EPS_) * mask[m];
  }
}

// ---------------- K2: pass 1 — local end states + u (bf16) ------------------
__global__ __launch_bounds__(256) void k_scan1(const float* __restrict__ hs,
                                               const float* __restrict__ nw,
                                               const float* __restrict__ scale,
                                               const float* __restrict__ wr_,
                                               const float* __restrict__ wi_,
                                               float* __restrict__ endr,
                                               float* __restrict__ endi,
                                               unsigned short* __restrict__ ubf) {
  int tid = threadIdx.x;
  int h = blockIdx.x * 256 + tid;
  int c = blockIdx.y, b = blockIdx.z;
  float wr[N_], wi[N_], xr[N_], xi[N_];
  #pragma unroll
  for (int n = 0; n < N_; n++) {
    wr[n] = wr_[n * H_ + h]; wi[n] = wi_[n * H_ + h];
    xr[n] = 0.f; xi[n] = 0.f;
  }
  float nwh = nw[h];
  int l0 = c * CH_;
  const float* scp = scale + (size_t)b * L_ + l0;   // block-uniform per l
  const float* hp = hs + ((size_t)b * L_ + l0) * H_ + h;
  unsigned short* up = ubf + ((size_t)b * L_ + l0) * H_ + h;
  #pragma unroll 8
  for (int l = 0; l < CH_; l++) {
    float u = hp[(size_t)l * H_] * scp[l] * nwh;
    unsigned short ub = f2bf(u);
    up[(size_t)l * H_] = ub;
    u = bf2f(ub);                 // keep scan consistent with stored u
    #pragma unroll
    for (int n = 0; n < N_; n++) {
      float oxr = xr[n];
      xr[n] = fmaf(wr[n], oxr, fmaf(-wi[n], xi[n], u));
      xi[n] = fmaf(wr[n], xi[n], wi[n] * oxr);
    }
  }
  size_t base = (((size_t)b * NC_ + c) * N_) * H_ + h;
  #pragma unroll
  for (int n = 0; n < N_; n++) {
    endr[base + (size_t)n * H_] = xr[n];
    endi[base + (size_t)n * H_] = xi[n];
  }
}

// ---------------- K3: pass 2 — carry scan, parallel over (b,n,h) ------------
__global__ __launch_bounds__(256) void k_carry(const float* __restrict__ wpr_,
                                               const float* __restrict__ wpi_,
                                               const float* __restrict__ endr,
                                               const float* __restrict__ endi,
                                               float* __restrict__ carr,
                                               float* __restrict__ cari) {
  int idx = blockIdx.x * 256 + threadIdx.x;   // B_*N_*H_ = 65536
  int h = idx & (H_ - 1);
  int n = (idx >> 10) & (N_ - 1);
  int b = idx >> 14;
  float wprv = wpr_[n * H_ + h], wpiv = wpi_[n * H_ + h];
  float sr = 0.f, si = 0.f;
  size_t cstride = (size_t)N_ * H_;
  size_t base = ((size_t)b * NC_) * cstride + (size_t)n * H_ + h;
  for (int c = 0; c < NC_; c++, base += cstride) {
    carr[base] = sr; cari[base] = si;
    float er = endr[base], ei = endi[base];
    float osr = sr;
    sr = fmaf(wprv, osr,  fmaf(-wpiv, si, er));
    si = fmaf(wprv, si, fmaf(wpiv, osr, ei));
  }
}

// ---------------- K4: pass 3 — n-outer re-scan from LDS u-tile --------------
__global__ __launch_bounds__(256) void k_scan2(const unsigned short* __restrict__ ubf,
                                               const float* __restrict__ wr_,
                                               const float* __restrict__ wi_,
                                               const float* __restrict__ c2r_,
                                               const float* __restrict__ c2i_,
                                               const float* __restrict__ Dp,
                                               const float* __restrict__ carr,
                                               const float* __restrict__ cari,
                                               unsigned short* __restrict__ ybf) {
  __shared__ __align__(16) unsigned short us[CH_ * 256];   // 32KB
  int tid = threadIdx.x;
  int hb = blockIdx.x;                 // h-block (4 of 256)
  int c = blockIdx.y, b = blockIdx.z;
  int h = hb * 256 + tid;
  int l0 = c * CH_;
  const unsigned short* usrc = ubf + ((size_t)b * L_ + l0) * H_ + hb * 256;
  #pragma unroll
  for (int i = 0; i < 8; i++) {
    int g = i * 256 + tid;
    int l = g >> 5, hq = (g & 31) * 8;
    async_copy16(usrc + (size_t)l * H_ + hq, &us[g * 8]);
  }
  __syncthreads();

  float yacc[CH_];
  float Dh = Dp[h];
  #pragma unroll
  for (int l = 0; l < CH_; l++)
    yacc[l] = Dh * bf2f(us[l * 256 + tid]);

  size_t base = (((size_t)b * NC_ + c) * N_) * H_ + h;
  for (int n = 0; n < N_; n++) {
    float wrv = wr_[n * H_ + h],  wiv = wi_[n * H_ + h];
    float crv = c2r_[n * H_ + h], civ = c2i_[n * H_ + h];
    float xr = carr[base + (size_t)n * H_];
    float xi = cari[base + (size_t)n * H_];
    #pragma unroll
    for (int l = 0; l < CH_; l++) {
      float u = bf2f(us[l * 256 + tid]);
      float oxr = xr;
      xr = fmaf(wrv, oxr, fmaf(-wiv, xi, u));
      xi = fmaf(wrv, xi, wiv * oxr);
      yacc[l] = fmaf(crv, xr, fmaf(-civ, xi, yacc[l]));
    }
  }
  unsigned short* yp = ybf + ((size_t)b * L_ + l0) * H_ + h;
  #pragma unroll
  for (int l = 0; l < CH_; l++) {
    float yv = yacc[l];
    float g = 0.5f * yv * (1.0f + erff(yv * 0.70710678118654752f));
    yp[(size_t)l * H_] = f2bf(g);
  }
}

// ---------------- K5: 256x256 8-phase GEMM + fused GLU/bias/residual --------
// Round-2 fix: fragment reuse across phases. Persistent regs afr[4][2] (A
// half for current mh), bf0/bf1[2][2] (both B n-halves). Per-phase ds_reads
// drop from 12 to (12,4,8,0) -> 24 reads/wave/K-tile (= tile read volume
// minimum). LDS time/CU/K-tile ~2.3k cyc < MFMA ~2.5k cyc -> MFMA becomes
// the critical path. MFMA order per output element unchanged.
//
// Region/drain schedule (t0=2i buf0, t1=2i+1 buf1, tc=2i+2, td=2i+3):
//   ph0: ldA(b0,m0)+ldB(b0,n0->bf0)  stage A1hi(t1)   mfma(0,0,bf0)
//   ph1: ldB(b0,n1->bf1)             stage B1ev(t1)   mfma(0,1,bf1)
//   ph2: ldA(b0,m1)                  stage A0lo(tc)   mfma(1,1,bf1)
//   ph3: -                           stage B0od(tc)   mfma(1,0,bf0)  VM4
//   ph4: ldA(b1,m0)+ldB(b1,n0->bf0)  stage A0hi(tc)   mfma(0,0,bf0)
//   ph5: ldB(b1,n1->bf1)             stage B0ev(tc)   mfma(0,1,bf1)
//   ph6: ldA(b1,m1)                  stage A1lo(td)   mfma(1,1,bf1)
//   ph7: -                           stage B1od(td)   mfma(1,0,bf0)  VM4
// VM4@ph3 drains all of buf1/t1 (needed ph4-6); VM4@ph7 drains all of
// buf0/tc (needed next ph0-2). Steady-state in-flight = 4 loads. Every
// stage target has >=2 barriers after its region's last ds_read.
#define BM2 256
#define BN2 256
#define NT2 16              // K tiles (K=1024, BK=64)
#define GST 132             // epilogue fp32 row stride (16B-aligned, 128 cols)
#define GEMM_LDS 131072

#define STAGE_A(buf, half, kt) do { \
  async_copy16(Ag + (size_t)(bm + rp0 + ((half) << 6)) * H_ + (kt) * 64 + ca0, \
               sA + (buf) * 32768 + ((half) << 13) + tid * 16); \
  async_copy16(Ag + (size_t)(bm + rp1 + 64 + ((half) << 6)) * H_ + (kt) * 64 + ca1, \
               sA + (buf) * 32768 + ((half) << 13) + 16384 + tid * 16); \
} while (0)

#define STAGE_B(buf, eo, kt) do { \
  async_copy16(Bg + (size_t)(bn + ((rp0 >> 5) << 6) + (rp0 & 31) + ((eo) << 5)) * H_ + (kt) * 64 + ca0, \
               sB + (buf) * 32768 + ((rp0 >> 5) << 13) + ((rp0 & 31) << 7) + ((eo) << 12) + (q0 << 4)); \
  async_copy16(Bg + (size_t)(bn + ((rp1 >> 5) << 6) + (rp1 & 31) + ((eo) << 5)) * H_ + (kt) * 64 + ca1, \
               sB + (buf) * 32768 + ((rp1 >> 5) << 13) + ((rp1 & 31) << 7) + ((eo) << 12) + (q0 << 4)); \
} while (0)

#define VM4  asm volatile("s_waitcnt vmcnt(4)" ::: "memory")
#define NOVM do {} while (0)
#define NOLOAD do {} while (0)

#define LOAD_A(buf, mh) do { \
  _Pragma("unroll") \
  for (int m2 = 0; m2 < 4; m2++) { \
    _Pragma("unroll") \
    for (int kk = 0; kk < 2; kk++) \
      afr[m2][kk] = *reinterpret_cast<const bf16x8*>( \
          sA + (buf) * 32768 + (((wm << 7) + ((mh) << 6) + (m2 << 4)) << 7) + aoff[kk]); \
  } \
} while (0)

#define LOAD_B(buf, nh, dst) do { \
  _Pragma("unroll") \
  for (int n2 = 0; n2 < 2; n2++) { \
    _Pragma("unroll") \
    for (int kk = 0; kk < 2; kk++) \
      dst[n2][kk] = *reinterpret_cast<const bf16x8*>( \
          sB + (buf) * 32768 + (((wn << 6) + ((nh) << 5) + (n2 << 4)) << 7) + aoff[kk]); \
  } \
} while (0)

#define PH(LOADS, STAGE_STMT, mh, nh, bfx, CLOSE_STMT) do { \
  LOADS; \
  STAGE_STMT; \
  asm volatile("" ::: "memory"); \
  __builtin_amdgcn_s_barrier(); \
  asm volatile("s_waitcnt lgkmcnt(0)" ::: "memory"); \
  __builtin_amdgcn_sched_barrier(0); \
  __builtin_amdgcn_s_setprio(1); \
  _Pragma("unroll") \
  for (int m2 = 0; m2 < 4; m2++) { \
    _Pragma("unroll") \
    for (int n2 = 0; n2 < 2; n2++) { \
      _Pragma("unroll") \
      for (int kk = 0; kk < 2; kk++) \
        acc[(mh) * 4 + m2][(nh) * 2 + n2] = __builtin_amdgcn_mfma_f32_16x16x32_bf16( \
            afr[m2][kk], bfx[n2][kk], acc[(mh) * 4 + m2][(nh) * 2 + n2], 0, 0, 0); \
    } \
  } \
  __builtin_amdgcn_s_setprio(0); \
  CLOSE_STMT; \
  asm volatile("" ::: "memory"); \
  __builtin_amdgcn_s_barrier(); \
  asm volatile("" ::: "memory"); \
} while (0)

__global__ __launch_bounds__(512, 2) void k_gemm(const unsigned short* __restrict__ Ag,
                                                 const unsigned short* __restrict__ Bg,
                                                 const float* __restrict__ bp,
                                                 const float* __restrict__ hs,
                                                 float* __restrict__ out) {
  extern __shared__ __align__(16) char smem[];
  char* sA = smem;                       // [2][256][64] bf16 = 64KB
  char* sB = smem + 65536;               // [2][256][64] bf16 = 64KB
  const int tid  = threadIdx.x;
  const int lane = tid & 63;
  const int wave = tid >> 6;
  const int wm = wave >> 2;              // 0..1  (row half, 128 rows)
  const int wn = wave & 3;               // 0..3  (col quarter, 64 cols)
  // T1: XCD-chunked bijective block swizzle (512 wgs, 8 XCDs -> 64/XCD).
  // Each XCD gets 8 contiguous bm-panels x all bn -> A panel reuse in L2.
  const int lin = blockIdx.y * 8 + blockIdx.x;    // gridDim.x == 8
  const int w   = ((lin & 7) << 6) + (lin >> 3);
  const int bn  = (w & 7) * BN2;
  const int bm  = (w >> 3) * BM2;
  const int ar = lane & 15, kqi = lane >> 4;

  // staging constants: issue i covers chunks i*512+tid; r' = chunk>>3
  const int rp0 = tid >> 3, q0 = tid & 7;
  const int rp1 = rp0 + 64;
  const int ca0 = (q0 ^ (rp0 & 7)) * 8;  // pre-swizzled source col (elements)
  const int ca1 = (q0 ^ (rp1 & 7)) * 8;
  // ds_read offsets: row&7 == ar&7 for every fragment row -> per-thread const
  int aoff[2];
  #pragma unroll
  for (int kk = 0; kk < 2; kk++)
    aoff[kk] = ar * 128 + (((kk * 4 + kqi) ^ (ar & 7)) << 4);

  f32x4 acc[8][4];
  #pragma unroll
  for (int mi = 0; mi < 8; mi++)
    #pragma unroll
    for (int ni = 0; ni < 4; ni++) acc[mi][ni] = (f32x4){0.f, 0.f, 0.f, 0.f};

  bf16x8 afr[4][2], bf0[2][2], bf1[2][2];

  // prologue: tile0 fully into buf0, then A-LOW/B-ODD of tile1 into buf1.
  // vmcnt(4) drains tile0's 4 stages, leaves tile1's 2 in flight.
  STAGE_A(0, 0, 0);
  STAGE_B(0, 0, 0);
  STAGE_A(0, 1, 0);
  STAGE_B(0, 1, 0);
  STAGE_A(1, 0, 1);
  STAGE_B(1, 1, 1);
  VM4;
  __builtin_amdgcn_s_barrier();
  asm volatile("" ::: "memory");

  #pragma unroll 1
  for (int i = 0; i < NT2 / 2; i++) {
    const int tb = 2 * i + 1;
    const int tc = (2 * i + 2 < NT2) ? 2 * i + 2 : NT2 - 1;  // clamped: last-iter
    const int td = (2 * i + 3 < NT2) ? 2 * i + 3 : NT2 - 1;  // stages are benign
    PH(LOAD_A(0, 0); LOAD_B(0, 0, bf0), STAGE_A(1, 1, tb), 0, 0, bf0, NOVM);
    PH(LOAD_B(0, 1, bf1),               STAGE_B(1, 0, tb), 0, 1, bf1, NOVM);
    PH(LOAD_A(0, 1),                    STAGE_A(0, 0, tc), 1, 1, bf1, NOVM);
    PH(NOLOAD,                          STAGE_B(0, 1, tc), 1, 0, bf0, VM4);
    PH(LOAD_A(1, 0); LOAD_B(1, 0, bf0), STAGE_A(0, 1, tc), 0, 0, bf0, NOVM);
    PH(LOAD_B(1, 1, bf1),               STAGE_B(0, 0, tc), 0, 1, bf1, NOVM);
    PH(LOAD_A(1, 1),                    STAGE_A(1, 0, td), 1, 1, bf1, NOVM);
    PH(NOLOAD,                          STAGE_B(1, 1, td), 1, 0, bf0, VM4);
  }
  asm volatile("s_waitcnt vmcnt(0)" ::: "memory");   // drain before LDS reuse
  __builtin_amdgcn_s_barrier();
  asm volatile("" ::: "memory");

  // Epilogue in two 128-row halves (gt = 128 x GST fp32 = 66KB, reuses smem).
  // C/D layout: col = lane&15, row = (lane>>4)*4 + reg. Even packed col p =
  // GLU 'a', odd = 'b' (adjacent lane, same row).
  float* gt = (float*)smem;
  #pragma unroll
  for (int hf = 0; hf < 2; hf++) {
    if (wm == hf) {
      #pragma unroll
      for (int ni = 0; ni < 4; ni++) {
        int p  = wn * 64 + ni * 16 + (lane & 15);
        int pe = (bn + p) & ~1;
        float bA = bp[pe], bB = bp[pe + 1];
        int jl = p >> 1;
        #pragma unroll
        for (int mi = 0; mi < 8; mi++) {
          int lrow0 = mi * 16 + (lane >> 4) * 4;
          #pragma unroll
          for (int r = 0; r < 4; r++) {
            float v = acc[mi][ni][r];
            float w2 = __shfl_xor(v, 1, 64);
            if (!(lane & 1))
              gt[(lrow0 + r) * GST + jl] = (v + bA) / (1.0f + __expf(-(w2 + bB)));
          }
        }
      }
    }
    __syncthreads();
    {
      const int c4 = tid & 31;             // 32 float4 = 128 output cols
      const int rw = tid >> 5;             // 0..15
      const size_t obase = (size_t)(bm + hf * 128) * H_ + (bn >> 1);
      #pragma unroll
      for (int rep = 0; rep < 8; rep++) {
        int row = rep * 16 + rw;
        float4 g = *reinterpret_cast<const float4*>(&gt[row * GST + c4 * 4]);
        size_t o = obase + (size_t)row * H_ + c4 * 4;
        float4 hv = *reinterpret_cast<const float4*>(&hs[o]);
        float4 rv = {hv.x + g.x, hv.y + g.y, hv.z + g.z, hv.w + g.w};
        *reinterpret_cast<float4*>(&out[o]) = rv;
      }
    }
    __syncthreads();
  }
}

extern "C" void kernel_launch(void* const* d_in, const int* in_sizes, int n_in,
                              void* d_out, int out_size, void* d_ws, size_t ws_size,
                              hipStream_t stream) {
  const float* hs    = (const float*)d_in[0];
  const float* mask  = (const float*)d_in[1];
  const float* nw    = (const float*)d_in[2];
  const float* ldt   = (const float*)d_in[3];
  const float* lar   = (const float*)d_in[4];
  const float* aim   = (const float*)d_in[5];
  const float* crl   = (const float*)d_in[6];
  const float* cim   = (const float*)d_in[7];
  const float* Dp    = (const float*)d_in[8];
  const float* outw  = (const float*)d_in[9];
  const float* outb  = (const float*)d_in[10];
  float* out = (float*)d_out;

  static bool attr_done = false;
  if (!attr_done) {
    hipFuncSetAttribute((const void*)k_gemm,
                        hipFuncAttributeMaxDynamicSharedMemorySize, GEMM_LDS);
    attr_done = true;
  }

  size_t off = 0;
  char* ws = (char*)d_ws;
  auto nxt = [&](size_t bytes) -> void* {
    void* p = ws + off; off += (bytes + 255) & ~(size_t)255; return p;
  };
  float* wr   = (float*)nxt(H_ * N_ * 4);
  float* wi   = (float*)nxt(H_ * N_ * 4);
  float* c2r  = (float*)nxt(H_ * N_ * 4);
  float* c2i  = (float*)nxt(H_ * N_ * 4);
  float* wpr  = (float*)nxt(H_ * N_ * 4);
  float* wpi  = (float*)nxt(H_ * N_ * 4);
  float* bpck = (float*)nxt(O2_ * 4);
  float* scale= (float*)nxt((size_t)M_ * 4);
  float* endr = (float*)nxt((size_t)B_ * NC_ * N_ * H_ * 4);
  float* endi = (float*)nxt((size_t)B_ * NC_ * N_ * H_ * 4);
  float* carr = (float*)nxt((size_t)B_ * NC_ * N_ * H_ * 4);
  float* cari = (float*)nxt((size_t)B_ * NC_ * N_ * H_ * 4);
  unsigned short* Wbf = (unsigned short*)nxt((size_t)O2_ * H_ * 2);
  unsigned short* ubf = (unsigned short*)nxt((size_t)M_ * H_ * 2);
  unsigned short* ybf = (unsigned short*)nxt((size_t)M_ * H_ * 2);

  k_prep<<<dim3(O2_ * H_ / 256), dim3(256), 0, stream>>>(ldt, lar, aim, crl, cim,
                                                         outw, outb,
                                                         wr, wi, c2r, c2i, wpr, wpi,
                                                         Wbf, bpck);
  k_scale<<<dim3(M_), dim3(256), 0, stream>>>(hs, mask, scale);
  k_scan1<<<dim3(H_ / 256, NC_, B_), dim3(256), 0, stream>>>(hs, nw, scale, wr, wi,
                                                             endr, endi, ubf);
  k_carry<<<dim3(B_ * N_ * H_ / 256), dim3(256), 0, stream>>>(wpr, wpi, endr, endi, carr, cari);
  k_scan2<<<dim3(H_ / 256, NC_, B_), dim3(256), 0, stream>>>(ubf, wr, wi, c2r, c2i,
                                                             Dp, carr, cari, ybf);
  k_gemm<<<dim3(O2_ / BN2, M_ / BM2), dim3(512), GEMM_LDS, stream>>>(ybf, Wbf, bpck, hs, out);
}